// Round 3
// baseline (731.207 us; speedup 1.0000x reference)
//
#include <hip/hip_runtime.h>

#define DD 256
#define KK 1024
#define HW 4096
#define NBATCH 16
#define NROWS (NBATCH * HW)          // 65536
#define OUT_Z (NBATCH * DD * HW)     // 16777216
#define OUT_IDX OUT_Z
#define OUT_LOSS (OUT_Z + NROWS)

// ws layout: [0, 256K) float zsq[65536]; [256K, 260K) float esq[1024]; [260K, +8) double lsum

// numpy pairwise_sum exact emulation for contiguous n=256:
// two blocks of 128; each block: 8 accumulators r[j] over elements == j (mod 8),
// combined ((r0+r1)+(r2+r3))+((r4+r5)+(r6+r7)); top-level: block0 + block1.
// __fmul_rn/__fadd_rn are never contracted into FMA by the compiler.

__global__ void vq_zsq(const float* __restrict__ z, float* __restrict__ zsq)
{
    int n = blockIdx.x * 256 + threadIdx.x;          // 65536 threads
    const float* p = z + (size_t)(n >> 12) * (DD * HW) + (n & (HW - 1));
    float blk[2];
#pragma unroll
    for (int b2 = 0; b2 < 2; ++b2) {
        const int p0 = b2 * 128;
        float r[8];
#pragma unroll
        for (int j = 0; j < 8; ++j) {
            float v = p[(size_t)(p0 + j) * HW];
            r[j] = __fmul_rn(v, v);
        }
        for (int i = 8; i < 128; i += 8) {
#pragma unroll
            for (int j = 0; j < 8; ++j) {
                float v = p[(size_t)(p0 + i + j) * HW];
                r[j] = __fadd_rn(r[j], __fmul_rn(v, v));
            }
        }
        blk[b2] = __fadd_rn(__fadd_rn(__fadd_rn(r[0], r[1]), __fadd_rn(r[2], r[3])),
                            __fadd_rn(__fadd_rn(r[4], r[5]), __fadd_rn(r[6], r[7])));
    }
    zsq[n] = __fadd_rn(blk[0], blk[1]);
}

__global__ void vq_prep(const float* __restrict__ emb, float* __restrict__ esq,
                        double* __restrict__ lsum)
{
    int k = blockIdx.x * 256 + threadIdx.x;
    if (k == 0 && blockIdx.x == 0) lsum[0] = 0.0;
    if (k < KK) {
        const float* e = emb + (size_t)k * DD;
        float blk[2];
#pragma unroll
        for (int b2 = 0; b2 < 2; ++b2) {
            const float* p = e + b2 * 128;
            float r[8];
#pragma unroll
            for (int j = 0; j < 8; ++j) r[j] = __fmul_rn(p[j], p[j]);
            for (int i = 8; i < 128; i += 8) {
#pragma unroll
                for (int j = 0; j < 8; ++j)
                    r[j] = __fadd_rn(r[j], __fmul_rn(p[i + j], p[i + j]));
            }
            blk[b2] = __fadd_rn(__fadd_rn(__fadd_rn(r[0], r[1]), __fadd_rn(r[2], r[3])),
                                __fadd_rn(__fadd_rn(r[4], r[5]), __fadd_rn(r[6], r[7])));
        }
        esq[k] = __fadd_rn(blk[0], blk[1]);
    }
}

__launch_bounds__(256, 3)
__global__ void vq_main(const float* __restrict__ z, const float* __restrict__ emb,
                        const float* __restrict__ zsq, const float* __restrict__ esq,
                        float* __restrict__ out, double* __restrict__ lsum)
{
    __shared__ union U {
        struct { float zt[32][64]; float et[32][260]; } s;  // 41.3 KB compute phase
        float2 cand[64][32];                                 // 16 KB merge phase
    } sm;
    __shared__ int   idxs[64];
    __shared__ float wsum[4];

    const int t   = threadIdx.x;
    const int n0  = blockIdx.x * 64;
    const int b   = n0 >> 12;
    const int hw0 = n0 & (HW - 1);
    const float* zbase = z + (size_t)b * DD * HW;

    const int tn = t & 7, tk = t >> 3;        // 8 n-groups x 32 k-groups
    const int tn8 = tn * 8, tk8 = tk * 8;

    float zq8[8];
#pragma unroll
    for (int i = 0; i < 8; ++i) zq8[i] = zsq[n0 + tn8 + i];

    float smin[8]; int kmin[8];
#pragma unroll
    for (int i = 0; i < 8; ++i) { smin[i] = 3.4e38f; kmin[i] = 0; }

    for (int kt = 0; kt < 4; ++kt) {
        float acc[8][8];
#pragma unroll
        for (int i = 0; i < 8; ++i)
#pragma unroll
            for (int j = 0; j < 8; ++j) acc[i][j] = 0.f;

        for (int dc = 0; dc < 8; ++dc) {
            const int d0 = dc * 32;
            __syncthreads();
            // stage z tile [32 d][64 n] (coalesced float2 along hw)
#pragma unroll
            for (int it = 0; it < 4; ++it) {
                int idx = it * 256 + t;
                int dd = idx >> 5, np = idx & 31;
                float2 v = *(const float2*)(zbase + (size_t)(d0 + dd) * HW + hw0 + np * 2);
                *(float2*)&sm.s.zt[dd][np * 2] = v;
            }
            // stage e tile [32 d][256 k], transposed from emb[k][d] (float4 along d)
#pragma unroll
            for (int it = 0; it < 8; ++it) {
                int idx = it * 256 + t;
                int kk = idx >> 3, dq = idx & 7;
                float4 v = *(const float4*)(emb + (size_t)(kt * 256 + kk) * DD + d0 + dq * 4);
                sm.s.et[dq * 4 + 0][kk] = v.x;
                sm.s.et[dq * 4 + 1][kk] = v.y;
                sm.s.et[dq * 4 + 2][kk] = v.z;
                sm.s.et[dq * 4 + 3][kk] = v.w;
            }
            __syncthreads();
            // sequential fp32 FMA over d (ascending) — BLAS microkernel accumulation model
#pragma unroll 8
            for (int dd = 0; dd < 32; ++dd) {
                float4 za  = *(const float4*)&sm.s.zt[dd][tn8];
                float4 zb4 = *(const float4*)&sm.s.zt[dd][tn8 + 4];
                float4 ea  = *(const float4*)&sm.s.et[dd][tk8];
                float4 eb  = *(const float4*)&sm.s.et[dd][tk8 + 4];
                float zv[8] = { za.x, za.y, za.z, za.w, zb4.x, zb4.y, zb4.z, zb4.w };
                float ev[8] = { ea.x, ea.y, ea.z, ea.w, eb.x, eb.y, eb.z, eb.w };
#pragma unroll
                for (int i = 0; i < 8; ++i)
#pragma unroll
                    for (int j = 0; j < 8; ++j)
                        acc[i][j] = fmaf(zv[i], ev[j], acc[i][j]);
            }
        }
        // fold: d = fp32(fp32(zsq + esq) - 2*dot), argmin with first-tie (ascending k, strict <)
#pragma unroll
        for (int j = 0; j < 8; ++j) {
            int k = kt * 256 + tk8 + j;
            float eq = esq[k];
#pragma unroll
            for (int i = 0; i < 8; ++i) {
                float t1 = __fadd_rn(zq8[i], eq);
                float s  = __fsub_rn(t1, __fmul_rn(2.0f, acc[i][j]));  // 2*acc exact
                if (s < smin[i]) { smin[i] = s; kmin[i] = k; }
            }
        }
    }

    __syncthreads();
#pragma unroll
    for (int i = 0; i < 8; ++i)
        sm.cand[tn8 + i][tk] = make_float2(smin[i], __int_as_float(kmin[i]));
    __syncthreads();

    if (t < 64) {
        float s1 = 3.4e38f; int k1 = 0x7fffffff;
        for (int g = 0; g < 32; ++g) {
            float2 c = sm.cand[t][g];
            float s = c.x; int k = __float_as_int(c.y);
            if (s < s1 || (s == s1 && k < k1)) { s1 = s; k1 = k; }
        }
        idxs[t] = k1;
        out[OUT_IDX + n0 + t] = (float)k1;   // indices stored as fp32 values
    }
    __syncthreads();

    // epilogue: scatter z_q back to NCHW + loss partial
    const int n  = t & 63;
    const int dg = t >> 6;
    const float* erow = emb + (size_t)idxs[n] * DD;
    const float* zc   = zbase + hw0 + n;
    float*       oc   = out + (size_t)b * DD * HW + hw0 + n;
    float lacc = 0.f;
#pragma unroll 4
    for (int dd = 0; dd < 64; ++dd) {
        int d = dg * 64 + dd;
        float e  = erow[d];
        float zv = zc[(size_t)d * HW];
        oc[(size_t)d * HW] = e;
        float df = e - zv;
        lacc = fmaf(df, df, lacc);
    }
#pragma unroll
    for (int off = 32; off > 0; off >>= 1) lacc += __shfl_down(lacc, off, 64);
    if ((t & 63) == 0) wsum[t >> 6] = lacc;
    __syncthreads();
    if (t == 0) {
        double tot = (double)wsum[0] + (double)wsum[1] + (double)wsum[2] + (double)wsum[3];
        atomicAdd(lsum, tot);
    }
}

__global__ void vq_final(const double* __restrict__ lsum, float* __restrict__ out)
{
    out[OUT_LOSS] = (float)(0.25 * (lsum[0] / (double)OUT_Z));
}

extern "C" void kernel_launch(void* const* d_in, const int* in_sizes, int n_in,
                              void* d_out, int out_size, void* d_ws, size_t ws_size,
                              hipStream_t stream)
{
    const float* z   = (const float*)d_in[0];
    const float* emb = (const float*)d_in[1];
    float* out = (float*)d_out;
    float* zsq = (float*)d_ws;
    float* esq = (float*)((char*)d_ws + NROWS * sizeof(float));
    double* lsum = (double*)((char*)d_ws + NROWS * sizeof(float) + KK * sizeof(float));

    vq_zsq <<<dim3(NROWS / 256), dim3(256), 0, stream>>>(z, zsq);
    vq_prep<<<dim3(4),           dim3(256), 0, stream>>>(emb, esq, lsum);
    vq_main<<<dim3(1024),        dim3(256), 0, stream>>>(z, emb, zsq, esq, out, lsum);
    vq_final<<<dim3(1), dim3(1), 0, stream>>>(lsum, out);
}

// Round 4
// 449.760 us; speedup vs baseline: 1.6258x; 1.6258x over previous
//
#include <hip/hip_runtime.h>

#define DD 256
#define KK 1024
#define HW 4096
#define NROWSZ 65536
#define OUT_Z 16777216
#define OUT_IDX OUT_Z
#define OUT_LOSS (OUT_Z + NROWSZ)

#define MARGIN 2.0e-4f

// ws layout (bytes)
#define WS_ZSQ   0          // float[65536]
#define WS_ESQ   262144     // float[1024]
#define WS_EH    266240     // _Float16[262144]  (emb rounded to fp16, row-major [k][d])
#define WS_COMB  790528     // u64[65536][8][2]  per-row per-kblock (top1, top2)
#define WS_HLIST 9179136    // int[65536]
#define WS_HCNT  9441280    // int
#define WS_LSUM  9441288    // double

typedef _Float16 f16x8 __attribute__((ext_vector_type(8)));
typedef float f32x4 __attribute__((ext_vector_type(4)));
union U16x8 { uint4 u; f16x8 h; };
typedef unsigned long long u64;

static __device__ __forceinline__ u64 umin64(u64 a, u64 b) { return a < b ? a : b; }
static __device__ __forceinline__ u64 umax64(u64 a, u64 b) { return a > b ? a : b; }

// ---------------- prep: zsq (numpy pairwise-8 exact), esq, eh, inits ----------------
__global__ void vq_prep(const float* __restrict__ z, const float* __restrict__ emb,
                        float* __restrict__ zsq, float* __restrict__ esq,
                        uint2* __restrict__ eh2, int* __restrict__ hcnt,
                        double* __restrict__ lsum)
{
    const int bid = blockIdx.x;
    const int t = threadIdx.x;
    if (bid == 0 && t == 0) { *hcnt = 0; *lsum = 0.0; }

    if (bid < 256) {
        // zsq: numpy pairwise_sum exact emulation (two 128-blocks of 8 accumulators)
        int n = bid * 256 + t;
        const float* p = z + (size_t)(n >> 12) * (DD * HW) + (n & (HW - 1));
        float blk[2];
#pragma unroll
        for (int b2 = 0; b2 < 2; ++b2) {
            const int p0 = b2 * 128;
            float r[8];
#pragma unroll
            for (int j = 0; j < 8; ++j) {
                float v = p[(size_t)(p0 + j) * HW];
                r[j] = __fmul_rn(v, v);
            }
            for (int i = 8; i < 128; i += 8) {
#pragma unroll
                for (int j = 0; j < 8; ++j) {
                    float v = p[(size_t)(p0 + i + j) * HW];
                    r[j] = __fadd_rn(r[j], __fmul_rn(v, v));
                }
            }
            blk[b2] = __fadd_rn(__fadd_rn(__fadd_rn(r[0], r[1]), __fadd_rn(r[2], r[3])),
                                __fadd_rn(__fadd_rn(r[4], r[5]), __fadd_rn(r[6], r[7])));
        }
        zsq[n] = __fadd_rn(blk[0], blk[1]);
    } else if (bid < 260) {
        // esq: same pairwise scheme over contiguous e-row
        int k = (bid - 256) * 256 + t;
        const float* e = emb + (size_t)k * DD;
        float blk[2];
#pragma unroll
        for (int b2 = 0; b2 < 2; ++b2) {
            const float* p = e + b2 * 128;
            float r[8];
#pragma unroll
            for (int j = 0; j < 8; ++j) r[j] = __fmul_rn(p[j], p[j]);
            for (int i = 8; i < 128; i += 8) {
#pragma unroll
                for (int j = 0; j < 8; ++j)
                    r[j] = __fadd_rn(r[j], __fmul_rn(p[i + j], p[i + j]));
            }
            blk[b2] = __fadd_rn(__fadd_rn(__fadd_rn(r[0], r[1]), __fadd_rn(r[2], r[3])),
                                __fadd_rn(__fadd_rn(r[4], r[5]), __fadd_rn(r[6], r[7])));
        }
        esq[k] = __fadd_rn(blk[0], blk[1]);
    } else {
        // eh: emb -> fp16, coalesced float4 -> 2x packed half2
        int tid = (bid - 260) * 256 + t;
        const float4* e4 = (const float4*)emb;
        for (int i = 0; i < 64; ++i) {
            int idx = i * 1024 + tid;       // 0..65535
            float4 v = e4[idx];
            _Float16 h0 = (_Float16)v.x, h1 = (_Float16)v.y;
            _Float16 h2 = (_Float16)v.z, h3 = (_Float16)v.w;
            uint2 o;
            o.x = (unsigned)__builtin_bit_cast(unsigned short, h0)
                | ((unsigned)__builtin_bit_cast(unsigned short, h1) << 16);
            o.y = (unsigned)__builtin_bit_cast(unsigned short, h2)
                | ((unsigned)__builtin_bit_cast(unsigned short, h3) << 16);
            eh2[idx] = o;
        }
    }
}

// ---------------- score: fp16-split MFMA GEMM + per-row top2 per 128-k block --------
// grid 4096: bk = blockIdx&7 (k-block of 128), bn = blockIdx>>3 (row-block of 128)
__launch_bounds__(256)
__global__ void vq_score(const float* __restrict__ z, const _Float16* __restrict__ eh,
                         const float* __restrict__ zsq, const float* __restrict__ esq,
                         u64* __restrict__ comb)
{
    __shared__ unsigned int aT0[16 * 132];   // zh: word(dp, n) = halves (d=2dp, 2dp+1)
    __shared__ unsigned int aT1[16 * 132];   // zl
    __shared__ _Float16 bT[128 * 32];        // eh tile [codeLocal][dd]

    const int t = threadIdx.x;
    const int lane = t & 63;
    const int w = t >> 6;
    const int col = lane & 15;
    const int quad = lane >> 4;

    const int bk = blockIdx.x & 7;
    const int bn = blockIdx.x >> 3;
    const int kb = bk * 128;
    const int N0 = bn * 128;
    const int b = N0 >> 12;
    const int hw0 = N0 & (HW - 1);
    const float* zbase = z + (size_t)b * DD * HW;

    f32x4 acc[2][8];
#pragma unroll
    for (int nt = 0; nt < 2; ++nt)
#pragma unroll
        for (int kt = 0; kt < 8; ++kt) acc[nt][kt] = (f32x4)0.0f;

    const int dp_s = t >> 4;          // staging d-pair 0..15
    const int ng_s = (t & 15) * 8;    // staging n-base
    const int cl_s = t >> 1;          // B staging local code
    const int hh_s = t & 1;

    for (int ds = 0; ds < 8; ++ds) {
        const int d0 = ds * 32;
        __syncthreads();
        // ---- stage A: global fp32 -> split fp16 hi/lo -> LDS (d-pair packed words)
        const float* p0 = zbase + (size_t)(d0 + 2 * dp_s) * HW + hw0 + ng_s;
        const float* p1 = p0 + HW;
        float4 a0 = *(const float4*)p0, a1 = *(const float4*)(p0 + 4);
        float4 c0 = *(const float4*)p1, c1 = *(const float4*)(p1 + 4);
        float ze0[8] = { a0.x, a0.y, a0.z, a0.w, a1.x, a1.y, a1.z, a1.w };
        float ze1[8] = { c0.x, c0.y, c0.z, c0.w, c1.x, c1.y, c1.z, c1.w };
#pragma unroll
        for (int i = 0; i < 8; ++i) {
            _Float16 h0 = (_Float16)ze0[i];
            _Float16 l0 = (_Float16)(ze0[i] - (float)h0);
            _Float16 h1 = (_Float16)ze1[i];
            _Float16 l1 = (_Float16)(ze1[i] - (float)h1);
            unsigned wh = (unsigned)__builtin_bit_cast(unsigned short, h0)
                        | ((unsigned)__builtin_bit_cast(unsigned short, h1) << 16);
            unsigned wl = (unsigned)__builtin_bit_cast(unsigned short, l0)
                        | ((unsigned)__builtin_bit_cast(unsigned short, l1) << 16);
            aT0[dp_s * 132 + ng_s + i] = wh;
            aT1[dp_s * 132 + ng_s + i] = wl;
        }
        // ---- stage B: eh tile copy (coalesced 32B per thread)
        {
            const _Float16* src = eh + (size_t)(kb + cl_s) * 256 + d0 + hh_s * 16;
            uint4 u0 = *(const uint4*)src;
            uint4 u1 = *(const uint4*)(src + 8);
            _Float16* dst = bT + cl_s * 32 + hh_s * 16;
            *(uint4*)dst = u0;
            *(uint4*)(dst + 8) = u1;
        }
        __syncthreads();
        // ---- compute: A-frags (zh,zl) x B-frags, 32 MFMAs
        U16x8 ah[2], al[2];
#pragma unroll
        for (int nt = 0; nt < 2; ++nt) {
            int nloc = w * 32 + nt * 16 + col;
            ah[nt].u.x = aT0[(quad * 4 + 0) * 132 + nloc];
            ah[nt].u.y = aT0[(quad * 4 + 1) * 132 + nloc];
            ah[nt].u.z = aT0[(quad * 4 + 2) * 132 + nloc];
            ah[nt].u.w = aT0[(quad * 4 + 3) * 132 + nloc];
            al[nt].u.x = aT1[(quad * 4 + 0) * 132 + nloc];
            al[nt].u.y = aT1[(quad * 4 + 1) * 132 + nloc];
            al[nt].u.z = aT1[(quad * 4 + 2) * 132 + nloc];
            al[nt].u.w = aT1[(quad * 4 + 3) * 132 + nloc];
        }
#pragma unroll
        for (int kt = 0; kt < 8; ++kt) {
            U16x8 bf;
            bf.u = *(const uint4*)(bT + (kt * 16 + col) * 32 + quad * 8);
            acc[0][kt] = __builtin_amdgcn_mfma_f32_16x16x32_f16(ah[0].h, bf.h, acc[0][kt], 0, 0, 0);
            acc[0][kt] = __builtin_amdgcn_mfma_f32_16x16x32_f16(al[0].h, bf.h, acc[0][kt], 0, 0, 0);
            acc[1][kt] = __builtin_amdgcn_mfma_f32_16x16x32_f16(ah[1].h, bf.h, acc[1][kt], 0, 0, 0);
            acc[1][kt] = __builtin_amdgcn_mfma_f32_16x16x32_f16(al[1].h, bf.h, acc[1][kt], 0, 0, 0);
        }
    }

    // ---- fold: per-row top2 (u64 packed) over this 128-k block
    float eqv[8];
#pragma unroll
    for (int kt = 0; kt < 8; ++kt) eqv[kt] = esq[kb + kt * 16 + col];

#pragma unroll
    for (int nt = 0; nt < 2; ++nt) {
#pragma unroll
        for (int r = 0; r < 4; ++r) {
            int rowloc = w * 32 + nt * 16 + quad * 4 + r;
            float zq = zsq[N0 + rowloc];
            u64 m1 = ~0ull, m2 = ~0ull;
#pragma unroll
            for (int kt = 0; kt < 8; ++kt) {
                float s = __fsub_rn(__fadd_rn(zq, eqv[kt]), __fmul_rn(2.0f, acc[nt][kt][r]));
                u64 p = ((u64)__float_as_uint(s) << 32) | (unsigned)(kb + kt * 16 + col);
                u64 mx = umax64(m1, p);
                m1 = umin64(m1, p);
                m2 = umin64(m2, mx);
            }
#pragma unroll
            for (int off = 1; off < 16; off <<= 1) {
                u64 o1 = __shfl_xor(m1, off, 16);
                u64 o2 = __shfl_xor(m2, off, 16);
                u64 mx = umax64(m1, o1);
                m1 = umin64(m1, o1);
                m2 = umin64(umin64(m2, o2), mx);
            }
            if (col == 0) {
                size_t o = ((size_t)(N0 + rowloc) * 8 + bk) * 2;
                comb[o] = m1;
                comb[o + 1] = m2;
            }
        }
    }
}

// ---------------- combine: merge 8 k-blocks, margin test, route hard rows ----------
__global__ void vq_combine(const u64* __restrict__ comb, float* __restrict__ out,
                           int* __restrict__ hlist, int* __restrict__ hcnt)
{
    int row = blockIdx.x * 256 + threadIdx.x;
    const u64* c = comb + (size_t)row * 16;
    u64 m1 = c[0], m2 = c[1];
#pragma unroll
    for (int i = 1; i < 8; ++i) {
        u64 v1 = c[2 * i], v2 = c[2 * i + 1];
        u64 mx = umax64(m1, v1);
        m1 = umin64(m1, v1);
        m2 = umin64(umin64(m2, v2), mx);
    }
    float s1 = __uint_as_float((unsigned)(m1 >> 32));
    float s2 = __uint_as_float((unsigned)(m2 >> 32));
    int k1 = (int)(m1 & 0xffffffffu);
    if (s2 > s1 + MARGIN) {
        out[OUT_IDX + row] = (float)k1;      // approx winner provably exact
    } else {
        int pos = atomicAdd(hcnt, 1);
        hlist[pos] = row;
    }
}

// ---------------- hard: bit-exact fp32 rescan of all 1024 codes for hard rows ------
// block = 8 rows x 1024 k; thread: 4 k (k = kk*256 + t) x 8 rows; d-chunks of 8
__launch_bounds__(256)
__global__ void vq_hard(const float* __restrict__ z, const float* __restrict__ emb,
                        const float* __restrict__ zsq, const float* __restrict__ esq,
                        const int* __restrict__ hlist, const int* __restrict__ hcnt,
                        float* __restrict__ out)
{
    __shared__ float e_lds[1024 * 12];   // pitch 12 floats (16B-aligned rows)
    __shared__ float z_lds[8][8];
    __shared__ float zq_s[8];
    __shared__ int rows_s[8];
    __shared__ u64 red[4][8];

    const int t = threadIdx.x;
    const int lane = t & 63;
    const int w = t >> 6;
    const int count = *hcnt;

    for (int g = blockIdx.x; g * 8 < count; g += gridDim.x) {
        if (t < 8) {
            int idx = g * 8 + t;
            int r = (idx < count) ? hlist[idx] : -1;
            rows_s[t] = r;
            int rr = (r < 0) ? 0 : r;
            zq_s[t] = zsq[rr];
        }
        __syncthreads();

        float acc_[8][4];
#pragma unroll
        for (int j = 0; j < 8; ++j)
#pragma unroll
            for (int kk = 0; kk < 4; ++kk) acc_[j][kk] = 0.0f;

        for (int dc = 0; dc < 32; ++dc) {
            const int d0 = dc * 8;
            __syncthreads();
            // stage e chunk: [1024 k][8 d]
#pragma unroll
            for (int s = 0; s < 4; ++s) {
                int k = s * 256 + t;
                const float* ep = emb + (size_t)k * DD + d0;
                float4 v0 = *(const float4*)ep;
                float4 v1 = *(const float4*)(ep + 4);
                *(float4*)&e_lds[k * 12] = v0;
                *(float4*)&e_lds[k * 12 + 4] = v1;
            }
            // stage z chunk: [8 rows][8 d]
            if (t < 64) {
                int j = t >> 3, dd = t & 7;
                int r = rows_s[j];
                int rr = (r < 0) ? 0 : r;
                z_lds[j][dd] = z[(size_t)(rr >> 12) * DD * HW + (size_t)(d0 + dd) * HW + (rr & (HW - 1))];
            }
            __syncthreads();
            // bit-exact sequential chains (d ascending)
#pragma unroll
            for (int kk = 0; kk < 4; ++kk) {
                int k = kk * 256 + t;
                float4 e0 = *(const float4*)&e_lds[k * 12];
                float4 e1 = *(const float4*)&e_lds[k * 12 + 4];
#pragma unroll
                for (int j = 0; j < 8; ++j) {
                    float4 z0 = *(const float4*)&z_lds[j][0];
                    float4 z1 = *(const float4*)&z_lds[j][4];
                    float a = acc_[j][kk];
                    a = fmaf(z0.x, e0.x, a);
                    a = fmaf(z0.y, e0.y, a);
                    a = fmaf(z0.z, e0.z, a);
                    a = fmaf(z0.w, e0.w, a);
                    a = fmaf(z1.x, e1.x, a);
                    a = fmaf(z1.y, e1.y, a);
                    a = fmaf(z1.z, e1.z, a);
                    a = fmaf(z1.w, e1.w, a);
                    acc_[j][kk] = a;
                }
            }
        }

        // exact scores + first-tie argmin (u64 pack: min score then min k)
        float eqv[4];
#pragma unroll
        for (int kk = 0; kk < 4; ++kk) eqv[kk] = esq[kk * 256 + t];

#pragma unroll
        for (int j = 0; j < 8; ++j) {
            u64 m = ~0ull;
#pragma unroll
            for (int kk = 0; kk < 4; ++kk) {
                int k = kk * 256 + t;
                float s = __fsub_rn(__fadd_rn(zq_s[j], eqv[kk]), __fmul_rn(2.0f, acc_[j][kk]));
                u64 p = ((u64)__float_as_uint(s) << 32) | (unsigned)k;
                m = umin64(m, p);
            }
#pragma unroll
            for (int off = 1; off < 64; off <<= 1)
                m = umin64(m, __shfl_xor(m, off, 64));
            if (lane == 0) red[w][j] = m;
            __syncthreads();
            if (t == 0) { /* noop to keep structure simple */ }
            __syncthreads();
        }
        if (t < 8) {
            u64 m = umin64(umin64(red[0][t], red[1][t]), umin64(red[2][t], red[3][t]));
            int r = rows_s[t];
            if (r >= 0) out[OUT_IDX + r] = (float)(int)(m & 0xffffffffu);
        }
        __syncthreads();
    }
}

// ---------------- finish: z_q scatter (NCHW) + loss partials ------------------------
__global__ void vq_finish(const float* __restrict__ z, const float* __restrict__ emb,
                          float* __restrict__ out, double* __restrict__ lsum)
{
    __shared__ int idxs[64];
    __shared__ float wsum[4];

    const int t = threadIdx.x;
    const int n0 = blockIdx.x * 64;
    const int b = n0 >> 12;
    const int hw0 = n0 & (HW - 1);

    if (t < 64) idxs[t] = (int)out[OUT_IDX + n0 + t];
    __syncthreads();

    const int n = t & 63;
    const int dg = t >> 6;
    const float* erow = emb + (size_t)idxs[n] * DD;
    const float* zc = z + (size_t)b * DD * HW + hw0 + n;
    float* oc = out + (size_t)b * DD * HW + hw0 + n;
    float lacc = 0.f;
#pragma unroll 4
    for (int dd = 0; dd < 64; ++dd) {
        int d = dg * 64 + dd;
        float e = erow[d];
        float zv = zc[(size_t)d * HW];
        oc[(size_t)d * HW] = e;
        float df = e - zv;
        lacc = fmaf(df, df, lacc);
    }
#pragma unroll
    for (int off = 32; off > 0; off >>= 1) lacc += __shfl_down(lacc, off, 64);
    if ((t & 63) == 0) wsum[t >> 6] = lacc;
    __syncthreads();
    if (t == 0) {
        double tot = (double)wsum[0] + (double)wsum[1] + (double)wsum[2] + (double)wsum[3];
        atomicAdd(lsum, tot);
    }
}

__global__ void vq_final(const double* __restrict__ lsum, float* __restrict__ out)
{
    out[OUT_LOSS] = (float)(0.25 * (lsum[0] / (double)OUT_Z));
}

extern "C" void kernel_launch(void* const* d_in, const int* in_sizes, int n_in,
                              void* d_out, int out_size, void* d_ws, size_t ws_size,
                              hipStream_t stream)
{
    const float* z = (const float*)d_in[0];
    const float* emb = (const float*)d_in[1];
    float* out = (float*)d_out;
    char* w = (char*)d_ws;

    float* zsq = (float*)(w + WS_ZSQ);
    float* esq = (float*)(w + WS_ESQ);
    _Float16* eh = (_Float16*)(w + WS_EH);
    uint2* eh2 = (uint2*)(w + WS_EH);
    u64* comb = (u64*)(w + WS_COMB);
    int* hlist = (int*)(w + WS_HLIST);
    int* hcnt = (int*)(w + WS_HCNT);
    double* lsum = (double*)(w + WS_LSUM);

    vq_prep<<<dim3(264), dim3(256), 0, stream>>>(z, emb, zsq, esq, eh2, hcnt, lsum);
    vq_score<<<dim3(4096), dim3(256), 0, stream>>>(z, eh, zsq, esq, comb);
    vq_combine<<<dim3(256), dim3(256), 0, stream>>>(comb, out, hlist, hcnt);
    vq_hard<<<dim3(512), dim3(256), 0, stream>>>(z, emb, zsq, esq, hlist, hcnt, out);
    vq_finish<<<dim3(1024), dim3(256), 0, stream>>>(z, emb, out, lsum);
    vq_final<<<dim3(1), dim3(1), 0, stream>>>(lsum, out);
}